// Round 5
// baseline (1288.471 us; speedup 1.0000x reference)
//
#include <hip/hip_runtime.h>

#define EPSF 1e-8f

constexpr int NB = 64;   // batch
constexpr int NO = 64;   // out capsules
constexpr int NI = 1152; // in capsules
constexpr int ND = 16;   // pose dims

// fp32 row loader ------------------------------------------------------------
__device__ __forceinline__ void loadrow16f(const float* __restrict__ base,
                                           size_t elem, float* f){
  const float4* p = (const float4*)(base + elem);
  float4 x0=p[0], x1=p[1], x2=p[2], x3=p[3];
  f[0]=x0.x; f[1]=x0.y; f[2]=x0.z; f[3]=x0.w;
  f[4]=x1.x; f[5]=x1.y; f[6]=x1.z; f[7]=x1.w;
  f[8]=x2.x; f[9]=x2.y; f[10]=x2.z; f[11]=x2.w;
  f[12]=x3.x; f[13]=x3.y; f[14]=x3.z; f[15]=x3.w;
}

// ---------------- kernel 1: a_i = ||u + eps||, asum[b] = sum_i a_i ----------
__global__ __launch_bounds__(256) void k_ai(const float* __restrict__ u,
                                            float* __restrict__ a_i,
                                            float* __restrict__ asum)
{
  const int b = blockIdx.x;
  const int t = threadIdx.x;
  float acc = 0.f;
  for (int i = t; i < NI; i += 256){
    float f[16];
    loadrow16f(u, ((size_t)b*NI + i)*ND, f);
    float s = 0.f;
    #pragma unroll
    for (int d=0; d<16; ++d){ float x = f[d] + EPSF; s += x*x; }
    float a = sqrtf(s);
    a_i[b*NI + i] = a;
    acc += a;
  }
  #pragma unroll
  for (int off=32; off; off>>=1) acc += __shfl_down(acc, off);
  __shared__ float r[4];
  if ((t & 63) == 0) r[t >> 6] = acc;
  __syncthreads();
  if (t == 0) asum[b] = r[0]+r[1]+r[2]+r[3];
}

// ---------------- kernel 2a: iter-0 m-step partials (uniform rr) ------------
// grid (b, c). block = 4 waves, all same b; lane = o; wave w takes quarter-chunk.
__global__ __launch_bounds__(256) void k_mpart(
    const float* __restrict__ u, const float* __restrict__ W,
    const float* __restrict__ bias, const float* __restrict__ a_i,
    float* __restrict__ S1p, float* __restrict__ S2p)
{
  const int CH  = gridDim.y;
  const int CHI = NI / CH, QI = CHI / 4;
  const int b = blockIdx.x, c = blockIdx.y;
  const int t = threadIdx.x, o = t & 63, w = t >> 6;

  float bs[16]; loadrow16f(bias, (size_t)o*ND, bs);
  float S1[16], S2[16];
  #pragma unroll
  for (int e=0;e<16;++e){ S1[e]=0.f; S2[e]=0.f; }

  for (int q=0; q<QI; ++q){
    const int i = c*CHI + w*QI + q;
    float uf[16]; loadrow16f(u, ((size_t)b*NI + i)*ND, uf);
    const float av = a_i[b*NI + i];
    const size_t wbase = ((size_t)o*NI + i)*(ND*ND);
    #pragma unroll
    for (int e=0;e<16;++e){
      float wf[16]; loadrow16f(W, wbase + (size_t)e*16, wf);
      float d0=0.f,d1=0.f,d2=0.f,d3=0.f;
      #pragma unroll
      for (int d=0; d<16; d+=4){
        d0 += uf[d+0]*wf[d+0]; d1 += uf[d+1]*wf[d+1];
        d2 += uf[d+2]*wf[d+2]; d3 += uf[d+3]*wf[d+3];
      }
      float V = ((d0+d1)+(d2+d3)) + EPSF + bs[e];
      float wv = av*V;
      S1[e] += wv;
      S2[e] += wv*V;
    }
  }
  // reduce 4 waves via LDS (stride 33: 2-way bank alias, free)
  __shared__ float red[3*64*33];
  if (w){
    float* d = &red[(((size_t)(w-1))*64 + o)*33];
    #pragma unroll
    for (int e=0;e<16;++e){ d[e]=S1[e]; d[16+e]=S2[e]; }
  }
  __syncthreads();
  if (!w){
    #pragma unroll
    for (int r=0;r<3;++r){
      const float* s = &red[(((size_t)r)*64 + o)*33];
      #pragma unroll
      for (int e=0;e<16;++e){ S1[e]+=s[e]; S2[e]+=s[16+e]; }
    }
    const size_t base = (((size_t)b*CH + c)*NO + o)*ND;
    #pragma unroll
    for (int e=0;e<16;++e){ S1p[base+e]=S1[e]; S2p[base+e]=S2[e]; }
  }
}

// ---------------- kernel 2b: reduce m-step partials -> mean0,i2v0,c0 --------
__global__ __launch_bounds__(64) void k_mred(
    const float* __restrict__ beta_a, const float* __restrict__ beta_u,
    const float* __restrict__ S1p, const float* __restrict__ S2p,
    const float* __restrict__ asum, const int CH,
    float* __restrict__ mean0, float* __restrict__ i2v0, float* __restrict__ c0)
{
  const int bo = blockIdx.x;
  const int b = bo >> 6, o = bo & 63;
  const int t = threadIdx.x;
  __shared__ float S1s[16], S2s[16];
  __shared__ float ct_s[16], vt_s[16];
  if (t < 16){
    float s = 0.f;
    for (int c=0;c<CH;++c) s += S1p[((((size_t)b*CH)+c)*NO + o)*ND + t];
    S1s[t] = s;
  } else if (t < 32){
    const int e = t - 16; float s = 0.f;
    for (int c=0;c<CH;++c) s += S2p[((((size_t)b*CH)+c)*NO + o)*ND + e];
    S2s[e] = s;
  }
  __syncthreads();
  if (t < 16){
    const float rrsum = asum[b] * (1.f/64.f);
    float T1 = S1s[t]*(1.f/64.f);
    float T2 = S2s[t]*(1.f/64.f);
    float m  = T1/(rrsum + EPSF);
    float var = (T2 - 2.f*m*T1 + m*m*rrsum)/(rrsum + EPSF) + 1e-4f;
    const size_t mbase = ((size_t)b*NO + o)*ND;
    mean0[mbase+t] = m;
    i2v0[mbase+t]  = 1.f/(2.f*var + EPSF);
    ct_s[t] = beta_u[o] + __logf(var);
    vt_s[t] = var;
  }
  __syncthreads();
  if (t == 0){
    const float rrsum = asum[b] * (1.f/64.f);
    float cost = 0.f, prod = 1.f;
    #pragma unroll
    for (int e=0;e<16;++e){ cost += ct_s[e]; prod *= vt_s[e]; }
    cost *= rrsum;
    float x  = 5.0e-4f*(beta_a[o] - cost);   // inv_temp iter0 = 0.01*(1-0.95)
    float aj = 1.f/(1.f + __expf(-x));
    float p1 = sqrtf(6.2831853071795864f*prod + EPSF);
    c0[(size_t)b*NO + o] = aj/(p1 + EPSF);
  }
}

// ---------------- kernel 3: fused e-step + iter-1 m-step partials -----------
// grid (b, c). block = 4 waves, same b; lane = o; wave w takes quarter-chunk.
__global__ __launch_bounds__(256) void k_epart(
    const float* __restrict__ u, const float* __restrict__ W,
    const float* __restrict__ bias, const float* __restrict__ a_i,
    const float* __restrict__ mean0, const float* __restrict__ i2v0,
    const float* __restrict__ c0,
    float* __restrict__ S1p, float* __restrict__ S2p, float* __restrict__ Wsp)
{
  const int CH  = gridDim.y;
  const int CHI = NI / CH, QI = CHI / 4;
  const int b = blockIdx.x, c = blockIdx.y;
  const int t = threadIdx.x, o = t & 63, w = t >> 6;

  float bs[16]; loadrow16f(bias, (size_t)o*ND, bs);
  float mr[16], ir[16];
  { const size_t mbase = ((size_t)b*NO + o)*ND;
    #pragma unroll
    for (int e=0;e<16;++e){ mr[e]=mean0[mbase+e]; ir[e]=i2v0[mbase+e]; } }
  const float c0r = c0[(size_t)b*NO + o];

  float S1[16], S2[16]; float wsum = 0.f;
  #pragma unroll
  for (int e=0;e<16;++e){ S1[e]=0.f; S2[e]=0.f; }

  for (int q=0; q<QI; ++q){
    const int i = c*CHI + w*QI + q;
    float uf[16]; loadrow16f(u, ((size_t)b*NI + i)*ND, uf);
    const float av = a_i[b*NI + i];
    const size_t wbase = ((size_t)o*NI + i)*(ND*ND);
    float V[16]; float la = 0.f;
    #pragma unroll
    for (int e=0;e<16;++e){
      float wf[16]; loadrow16f(W, wbase + (size_t)e*16, wf);
      float d0=0.f,d1=0.f,d2=0.f,d3=0.f;
      #pragma unroll
      for (int d=0; d<16; d+=4){
        d0 += uf[d+0]*wf[d+0]; d1 += uf[d+1]*wf[d+1];
        d2 += uf[d+2]*wf[d+2]; d3 += uf[d+3]*wf[d+3];
      }
      float Ve = ((d0+d1)+(d2+d3)) + EPSF + bs[e];
      V[e] = Ve;
      float df = Ve - mr[e];
      la += df*df*ir[e];
    }
    float ap = c0r*__expf(-la);
    float dsum = ap;
    #pragma unroll
    for (int off=32; off; off>>=1) dsum += __shfl_xor(dsum, off);
    float rr = ap/(dsum + EPSF);
    float wg = rr*av;
    wsum += wg;
    #pragma unroll
    for (int e=0;e<16;++e){ float tv = wg*V[e]; S1[e]+=tv; S2[e]+=tv*V[e]; }
  }
  // reduce 4 waves via LDS
  __shared__ float red[3*64*33];
  if (w){
    float* d = &red[(((size_t)(w-1))*64 + o)*33];
    #pragma unroll
    for (int e=0;e<16;++e){ d[e]=S1[e]; d[16+e]=S2[e]; }
    d[32] = wsum;
  }
  __syncthreads();
  if (!w){
    #pragma unroll
    for (int r=0;r<3;++r){
      const float* s = &red[(((size_t)r)*64 + o)*33];
      #pragma unroll
      for (int e=0;e<16;++e){ S1[e]+=s[e]; S2[e]+=s[16+e]; }
      wsum += s[32];
    }
    const size_t base = (((size_t)b*CH + c)*NO + o);
    #pragma unroll
    for (int e=0;e<16;++e){ S1p[base*ND+e]=S1[e]; S2p[base*ND+e]=S2[e]; }
    Wsp[base] = wsum;
  }
}

// ---------------- kernel 4: reduce partials, finalize output (fp32) ---------
__global__ __launch_bounds__(64) void k_final(
    const float* __restrict__ beta_a, const float* __restrict__ beta_u,
    const float* __restrict__ S1p, const float* __restrict__ S2p,
    const float* __restrict__ Wsp, const int CH,
    float* __restrict__ out)
{
  const int bo = blockIdx.x;
  const int b = bo >> 6, o = bo & 63;
  const int t = threadIdx.x;
  __shared__ float S1s[16], S2s[16], Wss;
  __shared__ float mean_s[16], ct_s[16], nt_s[16];
  __shared__ float scale_s;
  if (t < 16){
    float s = 0.f;
    for (int c=0;c<CH;++c) s += S1p[((((size_t)b*CH)+c)*NO + o)*ND + t];
    S1s[t] = s;
  } else if (t < 32){
    const int e = t - 16; float s = 0.f;
    for (int c=0;c<CH;++c) s += S2p[((((size_t)b*CH)+c)*NO + o)*ND + e];
    S2s[e] = s;
  } else if (t == 32){
    float s = 0.f;
    for (int c=0;c<CH;++c) s += Wsp[(((size_t)b*CH)+c)*NO + o];
    Wss = s;
  }
  __syncthreads();
  const float Wsum = Wss;
  if (t < 16){
    float S1 = S1s[t], S2 = S2s[t];
    float m = S1/(Wsum + EPSF);
    float var = (S2 - 2.f*m*S1 + m*m*Wsum)/(Wsum + EPSF) + 1e-4f;
    mean_s[t] = m;
    ct_s[t] = beta_u[o] + __logf(var);
    float me = m + EPSF;
    nt_s[t] = me*me;
  }
  __syncthreads();
  if (t == 0){
    float cost=0.f, nrm=0.f;
    #pragma unroll
    for (int e=0;e<16;++e){ cost += ct_s[e]; nrm += nt_s[e]; }
    cost *= Wsum;
    float x = 9.75e-4f*(beta_a[o] - cost);  // inv_temp iter1 = 0.01*(1-0.95^2)
    float aj = 1.f/(1.f + __expf(-x));
    scale_s = aj/(sqrtf(nrm) + EPSF);
  }
  __syncthreads();
  if (t < 16){
    out[(size_t)bo*ND + t] = scale_s*mean_s[t];   // fp32 store
  }
}

// ---------------- host ------------------------------------------------------
extern "C" void kernel_launch(void* const* d_in, const int* in_sizes, int n_in,
                              void* d_out, int out_size, void* d_ws, size_t ws_size,
                              hipStream_t stream)
{
  const float* u      = (const float*)d_in[0];
  const float* W      = (const float*)d_in[1];
  const float* beta_a = (const float*)d_in[2];
  const float* beta_u = (const float*)d_in[3];
  const float* bias   = (const float*)d_in[4];
  float* ws  = (float*)d_ws;
  float* out = (float*)d_out;

  const size_t base_f = (size_t)NB*NI + NB + 2u*NB*NO*ND + NB*NO;   // 208,960 floats
  const size_t per_ch = 2u*(size_t)NB*NO*ND + (size_t)NB*NO;       // 135,168 floats/chunk
  int CH = 2;
  if      (ws_size >= (base_f + per_ch*32)*4) CH = 32;
  else if (ws_size >= (base_f + per_ch*8 )*4) CH = 8;

  float* a_i  = ws;
  float* asum = a_i  + NB*NI;
  float* mean0= asum + NB;
  float* i2v0 = mean0 + (size_t)NB*NO*ND;
  float* c0   = i2v0 + (size_t)NB*NO*ND;
  float* S1p  = c0   + (size_t)NB*NO;
  float* S2p  = S1p  + (size_t)NB*CH*NO*ND;
  float* Wsp  = S2p  + (size_t)NB*CH*NO*ND;

  k_ai<<<NB, 256, 0, stream>>>(u, a_i, asum);
  k_mpart<<<dim3(NB, CH), 256, 0, stream>>>(u, W, bias, a_i, S1p, S2p);
  k_mred<<<NB*NO, 64, 0, stream>>>(beta_a, beta_u, S1p, S2p, asum, CH,
                                   mean0, i2v0, c0);
  k_epart<<<dim3(NB, CH), 256, 0, stream>>>(u, W, bias, a_i, mean0, i2v0, c0,
                                            S1p, S2p, Wsp);
  k_final<<<NB*NO, 64, 0, stream>>>(beta_a, beta_u, S1p, S2p, Wsp, CH, out);
}

// Round 6
// 1104.235 us; speedup vs baseline: 1.1668x; 1.1668x over previous
//
#include <hip/hip_runtime.h>

#define EPSF 1e-8f

constexpr int NB = 64;   // batch
constexpr int NO = 64;   // out capsules
constexpr int NI = 1152; // in capsules
constexpr int ND = 16;   // pose dims

// fp32 row loader ------------------------------------------------------------
__device__ __forceinline__ void loadrow16f(const float* __restrict__ base,
                                           size_t elem, float* f){
  const float4* p = (const float4*)(base + elem);
  float4 x0=p[0], x1=p[1], x2=p[2], x3=p[3];
  f[0]=x0.x; f[1]=x0.y; f[2]=x0.z; f[3]=x0.w;
  f[4]=x1.x; f[5]=x1.y; f[6]=x1.z; f[7]=x1.w;
  f[8]=x2.x; f[9]=x2.y; f[10]=x2.z; f[11]=x2.w;
  f[12]=x3.x; f[13]=x3.y; f[14]=x3.z; f[15]=x3.w;
}

// ---------------- kernel 1: a_i = ||u + eps||, asum[b] = sum_i a_i ----------
__global__ __launch_bounds__(256) void k_ai(const float* __restrict__ u,
                                            float* __restrict__ a_i,
                                            float* __restrict__ asum)
{
  const int b = blockIdx.x;
  const int t = threadIdx.x;
  float acc = 0.f;
  for (int i = t; i < NI; i += 256){
    float f[16];
    loadrow16f(u, ((size_t)b*NI + i)*ND, f);
    float s = 0.f;
    #pragma unroll
    for (int d=0; d<16; ++d){ float x = f[d] + EPSF; s += x*x; }
    float a = sqrtf(s);
    a_i[b*NI + i] = a;
    acc += a;
  }
  #pragma unroll
  for (int off=32; off; off>>=1) acc += __shfl_down(acc, off);
  __shared__ float r[4];
  if ((t & 63) == 0) r[t >> 6] = acc;
  __syncthreads();
  if (t == 0) asum[b] = r[0]+r[1]+r[2]+r[3];
}

// ---------------- heavy kernel: coalesced W, LDS V-tile, fused phase 2 ------
// grid (NB/2, CH). block = 256 thr = 4 waves, serves b0=2*bg, b1=2*bg+1.
// Phase 1: wave w stages V for i = i0+w, all 64 o, both b. Lane = (e=l>>2, j=l&3):
//   whole wave loads W[o,i,:,:] as 64x float4 = 1KB fully coalesced.
// Phase 2: lane = o; wave w -> b_local = w>>1, i_locals {(w&1)*2, +1}; softmax
//   over o is a wave-wide shuffle; moments accumulate in registers.
template<bool ESTEP>
__global__ __launch_bounds__(256) void k_heavy(
    const float* __restrict__ u, const float* __restrict__ W,
    const float* __restrict__ bias, const float* __restrict__ a_i,
    const float* __restrict__ mean0, const float* __restrict__ i2v0,
    const float* __restrict__ c0,
    float* __restrict__ S1p, float* __restrict__ S2p, float* __restrict__ Wsp)
{
  const int CH  = gridDim.y;
  const int CHI = NI / CH;
  const int TILES = CHI / 4;
  const int bg = blockIdx.x, c = blockIdx.y;
  const int t = threadIdx.x, lane = t & 63, w = t >> 6;
  const int bl = w >> 1;             // phase-2 batch-local
  const int b2 = bg*2 + bl;          // phase-2 batch
  const int e4 = lane >> 2, j4 = lane & 3;

  __shared__ float smem[8*64*17];    // V tiles [b][il][o][17]; tail reused for red

  // phase-2 per-lane constants (lane = o)
  float bs[16]; loadrow16f(bias, (size_t)lane*ND, bs);
  float mr[16], ir[16]; float c0r = 0.f;
  if (ESTEP){
    const size_t mbase = ((size_t)b2*NO + lane)*ND;
    #pragma unroll
    for (int e=0;e<16;++e){ mr[e]=mean0[mbase+e]; ir[e]=i2v0[mbase+e]; }
    c0r = c0[(size_t)b2*NO + lane];
  }

  float S1[16], S2[16]; float wsum = 0.f;
  #pragma unroll
  for (int e=0;e<16;++e){ S1[e]=0.f; S2[e]=0.f; }

  for (int tile=0; tile<TILES; ++tile){
    const int i0 = c*CHI + tile*4;
    // ---- phase 1: stage V (raw dot + EPS) into LDS, coalesced W loads ----
    {
      const int i = i0 + w;          // wave w -> i-local w
      const float4 ua = *(const float4*)(u + ((size_t)(bg*2+0)*NI + i)*ND + j4*4);
      const float4 ub = *(const float4*)(u + ((size_t)(bg*2+1)*NI + i)*ND + j4*4);
      #pragma unroll 4
      for (int o=0; o<64; ++o){
        const float4 wv = *(const float4*)(W + ((size_t)o*NI + i)*(ND*ND) + lane*4);
        float pa = wv.x*ua.x + wv.y*ua.y + wv.z*ua.z + wv.w*ua.w;
        float pb = wv.x*ub.x + wv.y*ub.y + wv.z*ub.z + wv.w*ub.w;
        pa += __shfl_xor(pa, 1); pa += __shfl_xor(pa, 2);
        pb += __shfl_xor(pb, 1); pb += __shfl_xor(pb, 2);
        if (j4 == 0){
          smem[((size_t)(0*4 + w)*64 + o)*17 + e4] = pa + EPSF;
          smem[((size_t)(1*4 + w)*64 + o)*17 + e4] = pb + EPSF;
        }
      }
    }
    __syncthreads();
    // ---- phase 2: consume V (lane = o) ----
    #pragma unroll
    for (int k=0; k<2; ++k){
      const int il = (w & 1)*2 + k;
      const int i  = i0 + il;
      const float av = a_i[(size_t)b2*NI + i];
      float V[16];
      { const float* s = &smem[((size_t)(bl*4 + il)*64 + lane)*17];
        #pragma unroll
        for (int e=0;e<16;++e) V[e] = s[e] + bs[e]; }
      float wg;
      if (ESTEP){
        float la = 0.f;
        #pragma unroll
        for (int e=0;e<16;++e){ float df = V[e]-mr[e]; la += df*df*ir[e]; }
        float ap = c0r*__expf(-la);
        float dsum = ap;
        #pragma unroll
        for (int off=32; off; off>>=1) dsum += __shfl_xor(dsum, off);
        float rr = ap/(dsum + EPSF);
        wg = rr*av;
        wsum += wg;
      } else {
        wg = av;
      }
      #pragma unroll
      for (int e=0;e<16;++e){ float tv = wg*V[e]; S1[e]+=tv; S2[e]+=tv*V[e]; }
    }
    __syncthreads();
  }

  // ---- cross-wave reduce (waves 1,3 dump; waves 0,2 combine + store) ----
  if (w & 1){
    float* d = &smem[((size_t)(w>>1)*64 + lane)*33];
    #pragma unroll
    for (int e=0;e<16;++e){ d[e]=S1[e]; d[16+e]=S2[e]; }
    d[32] = wsum;
  }
  __syncthreads();
  if (!(w & 1)){
    const float* s = &smem[((size_t)(w>>1)*64 + lane)*33];
    #pragma unroll
    for (int e=0;e<16;++e){ S1[e]+=s[e]; S2[e]+=s[16+e]; }
    wsum += s[32];
    const size_t base = (((size_t)b2*CH + c)*NO + lane);
    #pragma unroll
    for (int e=0;e<16;++e){ S1p[base*ND+e]=S1[e]; S2p[base*ND+e]=S2[e]; }
    if (ESTEP) Wsp[base] = wsum;
  }
}

// ---------------- reduce m-step partials -> mean0,i2v0,c0 -------------------
__global__ __launch_bounds__(64) void k_mred(
    const float* __restrict__ beta_a, const float* __restrict__ beta_u,
    const float* __restrict__ S1p, const float* __restrict__ S2p,
    const float* __restrict__ asum, const int CH,
    float* __restrict__ mean0, float* __restrict__ i2v0, float* __restrict__ c0)
{
  const int bo = blockIdx.x;
  const int b = bo >> 6, o = bo & 63;
  const int t = threadIdx.x;
  __shared__ float S1s[16], S2s[16];
  __shared__ float ct_s[16], vt_s[16];
  if (t < 16){
    float s = 0.f;
    for (int c=0;c<CH;++c) s += S1p[((((size_t)b*CH)+c)*NO + o)*ND + t];
    S1s[t] = s;
  } else if (t < 32){
    const int e = t - 16; float s = 0.f;
    for (int c=0;c<CH;++c) s += S2p[((((size_t)b*CH)+c)*NO + o)*ND + e];
    S2s[e] = s;
  }
  __syncthreads();
  if (t < 16){
    const float rrsum = asum[b] * (1.f/64.f);
    float T1 = S1s[t]*(1.f/64.f);
    float T2 = S2s[t]*(1.f/64.f);
    float m  = T1/(rrsum + EPSF);
    float var = (T2 - 2.f*m*T1 + m*m*rrsum)/(rrsum + EPSF) + 1e-4f;
    const size_t mbase = ((size_t)b*NO + o)*ND;
    mean0[mbase+t] = m;
    i2v0[mbase+t]  = 1.f/(2.f*var + EPSF);
    ct_s[t] = beta_u[o] + __logf(var);
    vt_s[t] = var;
  }
  __syncthreads();
  if (t == 0){
    const float rrsum = asum[b] * (1.f/64.f);
    float cost = 0.f, prod = 1.f;
    #pragma unroll
    for (int e=0;e<16;++e){ cost += ct_s[e]; prod *= vt_s[e]; }
    cost *= rrsum;
    float x  = 5.0e-4f*(beta_a[o] - cost);   // inv_temp iter0 = 0.01*(1-0.95)
    float aj = 1.f/(1.f + __expf(-x));
    float p1 = sqrtf(6.2831853071795864f*prod + EPSF);
    c0[(size_t)b*NO + o] = aj/(p1 + EPSF);
  }
}

// ---------------- final: reduce e-partials, write output (fp32) -------------
__global__ __launch_bounds__(64) void k_final(
    const float* __restrict__ beta_a, const float* __restrict__ beta_u,
    const float* __restrict__ S1p, const float* __restrict__ S2p,
    const float* __restrict__ Wsp, const int CH,
    float* __restrict__ out)
{
  const int bo = blockIdx.x;
  const int b = bo >> 6, o = bo & 63;
  const int t = threadIdx.x;
  __shared__ float S1s[16], S2s[16], Wss;
  __shared__ float mean_s[16], ct_s[16], nt_s[16];
  __shared__ float scale_s;
  if (t < 16){
    float s = 0.f;
    for (int c=0;c<CH;++c) s += S1p[((((size_t)b*CH)+c)*NO + o)*ND + t];
    S1s[t] = s;
  } else if (t < 32){
    const int e = t - 16; float s = 0.f;
    for (int c=0;c<CH;++c) s += S2p[((((size_t)b*CH)+c)*NO + o)*ND + e];
    S2s[e] = s;
  } else if (t == 32){
    float s = 0.f;
    for (int c=0;c<CH;++c) s += Wsp[(((size_t)b*CH)+c)*NO + o];
    Wss = s;
  }
  __syncthreads();
  const float Wsum = Wss;
  if (t < 16){
    float S1 = S1s[t], S2 = S2s[t];
    float m = S1/(Wsum + EPSF);
    float var = (S2 - 2.f*m*S1 + m*m*Wsum)/(Wsum + EPSF) + 1e-4f;
    mean_s[t] = m;
    ct_s[t] = beta_u[o] + __logf(var);
    float me = m + EPSF;
    nt_s[t] = me*me;
  }
  __syncthreads();
  if (t == 0){
    float cost=0.f, nrm=0.f;
    #pragma unroll
    for (int e=0;e<16;++e){ cost += ct_s[e]; nrm += nt_s[e]; }
    cost *= Wsum;
    float x = 9.75e-4f*(beta_a[o] - cost);  // inv_temp iter1 = 0.01*(1-0.95^2)
    float aj = 1.f/(1.f + __expf(-x));
    scale_s = aj/(sqrtf(nrm) + EPSF);
  }
  __syncthreads();
  if (t < 16){
    out[(size_t)bo*ND + t] = scale_s*mean_s[t];   // fp32 store
  }
}

// ---------------- host ------------------------------------------------------
extern "C" void kernel_launch(void* const* d_in, const int* in_sizes, int n_in,
                              void* d_out, int out_size, void* d_ws, size_t ws_size,
                              hipStream_t stream)
{
  const float* u      = (const float*)d_in[0];
  const float* W      = (const float*)d_in[1];
  const float* beta_a = (const float*)d_in[2];
  const float* beta_u = (const float*)d_in[3];
  const float* bias   = (const float*)d_in[4];
  float* ws  = (float*)d_ws;
  float* out = (float*)d_out;

  const size_t base_f = (size_t)NB*NI + NB + 2u*NB*NO*ND + NB*NO;   // 208,960 floats
  const size_t per_ch = 2u*(size_t)NB*NO*ND + (size_t)NB*NO;       // 135,168 floats/chunk
  int CH = 2;
  if      (ws_size >= (base_f + per_ch*32)*4) CH = 32;
  else if (ws_size >= (base_f + per_ch*8 )*4) CH = 8;

  float* a_i  = ws;
  float* asum = a_i  + NB*NI;
  float* mean0= asum + NB;
  float* i2v0 = mean0 + (size_t)NB*NO*ND;
  float* c0   = i2v0 + (size_t)NB*NO*ND;
  float* S1p  = c0   + (size_t)NB*NO;
  float* S2p  = S1p  + (size_t)NB*CH*NO*ND;
  float* Wsp  = S2p  + (size_t)NB*CH*NO*ND;

  k_ai<<<NB, 256, 0, stream>>>(u, a_i, asum);
  k_heavy<false><<<dim3(NB/2, CH), 256, 0, stream>>>(u, W, bias, a_i,
                                                     nullptr, nullptr, nullptr,
                                                     S1p, S2p, nullptr);
  k_mred<<<NB*NO, 64, 0, stream>>>(beta_a, beta_u, S1p, S2p, asum, CH,
                                   mean0, i2v0, c0);
  k_heavy<true><<<dim3(NB/2, CH), 256, 0, stream>>>(u, W, bias, a_i,
                                                    mean0, i2v0, c0,
                                                    S1p, S2p, Wsp);
  k_final<<<NB*NO, 64, 0, stream>>>(beta_a, beta_u, S1p, S2p, Wsp, CH, out);
}

// Round 7
// 475.298 us; speedup vs baseline: 2.7109x; 2.3232x over previous
//
#include <hip/hip_runtime.h>

#define EPSF 1e-8f

constexpr int NB = 64;   // batch
constexpr int NO = 64;   // out capsules
constexpr int NI = 1152; // in capsules
constexpr int ND = 16;   // pose dims

// fp32 row loader ------------------------------------------------------------
__device__ __forceinline__ void loadrow16f(const float* __restrict__ base,
                                           size_t elem, float* f){
  const float4* p = (const float4*)(base + elem);
  float4 x0=p[0], x1=p[1], x2=p[2], x3=p[3];
  f[0]=x0.x; f[1]=x0.y; f[2]=x0.z; f[3]=x0.w;
  f[4]=x1.x; f[5]=x1.y; f[6]=x1.z; f[7]=x1.w;
  f[8]=x2.x; f[9]=x2.y; f[10]=x2.z; f[11]=x2.w;
  f[12]=x3.x; f[13]=x3.y; f[14]=x3.z; f[15]=x3.w;
}

// ---------------- kernel 1: asum[b] = sum_i ||u[b,i,:] + eps|| --------------
__global__ __launch_bounds__(256) void k_ai(const float* __restrict__ u,
                                            float* __restrict__ asum)
{
  const int b = blockIdx.x;
  const int t = threadIdx.x;
  float acc = 0.f;
  for (int i = t; i < NI; i += 256){
    float f[16];
    loadrow16f(u, ((size_t)b*NI + i)*ND, f);
    float s = 0.f;
    #pragma unroll
    for (int d=0; d<16; ++d){ float x = f[d] + EPSF; s += x*x; }
    acc += sqrtf(s);
  }
  #pragma unroll
  for (int off=32; off; off>>=1) acc += __shfl_down(acc, off);
  __shared__ float r[4];
  if ((t & 63) == 0) r[t >> 6] = acc;
  __syncthreads();
  if (t == 0) asum[b] = r[0]+r[1]+r[2]+r[3];
}

// ---------------- heavy kernel: W staged once in LDS, 8 batches/block -------
// 1-D grid: bid = bg*CH + c  (same-c blocks share bid%8 -> same XCD -> W slice
// stays in that XCD's L2). Block = 4 waves; wave w owns batches b0=bg*8+2w,+1.
// Per i: stage W[:,i,:,:] (64KB) into LDS (swizzled), every lane (=o) computes
// V[o][e] for its 2 batches from LDS broadcast reads; softmax over o is a
// wave shuffle; moments accumulate in registers. W global traffic: 8x total.
// LDS layout: wsm[ed*64 + (o ^ ((ed>>1)&31))], ed = e*16+d.
//   write (fixed o=k, lanes ed=t): pairs t,t^1 share bank -> 2-way, free.
//   read  (fixed ed, lanes o): xor bijection -> banks distinct, free.
template<bool ESTEP>
__global__ __launch_bounds__(256, 1) void k_heavy(
    const float* __restrict__ u, const float* __restrict__ W,
    const float* __restrict__ bias,
    const float* __restrict__ mean0, const float* __restrict__ i2v0,
    const float* __restrict__ c0,
    float* __restrict__ S1p, float* __restrict__ S2p, float* __restrict__ Wsp,
    const int CH)
{
  const int CI = NI / CH;
  const int bid = blockIdx.x;
  const int bg = bid / CH, c = bid % CH;
  const int t = threadIdx.x, lane = t & 63, w = t >> 6;
  const int b0 = bg*8 + 2*w, b1 = b0 + 1;
  const int i0 = c*CI;

  __shared__ float wsm[256*64];   // exactly 64 KB

  // per-lane (=o) constants
  float bs[16]; loadrow16f(bias, (size_t)lane*ND, bs);
  float mr0[16], ir0[16], mr1[16], ir1[16]; float c00 = 0.f, c01 = 0.f;
  if (ESTEP){
    const size_t m0 = ((size_t)b0*NO + lane)*ND;
    const size_t m1 = ((size_t)b1*NO + lane)*ND;
    #pragma unroll
    for (int e=0;e<16;++e){ mr0[e]=mean0[m0+e]; ir0[e]=i2v0[m0+e];
                            mr1[e]=mean0[m1+e]; ir1[e]=i2v0[m1+e]; }
    c00 = c0[(size_t)b0*NO + lane];
    c01 = c0[(size_t)b1*NO + lane];
  }

  float S1a[16], S2a[16], S1b[16], S2b[16];
  float wsa = 0.f, wsb = 0.f;
  #pragma unroll
  for (int e=0;e<16;++e){ S1a[e]=0.f; S2a[e]=0.f; S1b[e]=0.f; S2b[e]=0.f; }

  // prefetch W row i0: thread t holds column ed=t of all 64 o-rows
  float pf[64];
  #pragma unroll
  for (int k=0;k<64;++k) pf[k] = W[((size_t)k*NI + i0)*256 + t];

  for (int ii=0; ii<CI; ++ii){
    const int i = i0 + ii;
    __syncthreads();                       // everyone done reading old tile
    #pragma unroll
    for (int k=0;k<64;++k) wsm[t*64 + (k ^ ((t>>1)&31))] = pf[k];
    __syncthreads();                       // tile ready
    if (ii+1 < CI){                        // prefetch next tile (hidden by compute)
      const int ip = i + 1;
      #pragma unroll
      for (int k=0;k<64;++k) pf[k] = W[((size_t)k*NI + ip)*256 + t];
    }

    // u rows (wave-uniform addresses -> broadcast)
    float u0[16], u1[16];
    loadrow16f(u, ((size_t)b0*NI + i)*ND, u0);
    loadrow16f(u, ((size_t)b1*NI + i)*ND, u1);
    // inline a_i
    float s0=0.f, s1=0.f;
    #pragma unroll
    for (int d=0;d<16;++d){
      float x0=u0[d]+EPSF; s0 += x0*x0;
      float x1=u1[d]+EPSF; s1 += x1*x1;
    }
    const float av0 = sqrtf(s0), av1 = sqrtf(s1);

    // V for this lane's o, both batches
    float V0[16], V1[16];
    #pragma unroll
    for (int e=0;e<16;++e){ V0[e]=bs[e]+EPSF; V1[e]=bs[e]+EPSF; }
    #pragma unroll
    for (int e=0;e<16;++e){
      #pragma unroll
      for (int d=0;d<16;++d){
        const int ed = e*16+d;
        const float wv = wsm[ed*64 + (lane ^ ((ed>>1)&31))];
        V0[e] += wv*u0[d];
        V1[e] += wv*u1[d];
      }
    }

    float wg0, wg1;
    if (ESTEP){
      float la0=0.f, la1=0.f;
      #pragma unroll
      for (int e=0;e<16;++e){
        float d0=V0[e]-mr0[e]; la0 += d0*d0*ir0[e];
        float d1=V1[e]-mr1[e]; la1 += d1*d1*ir1[e];
      }
      float ap0 = c00*__expf(-la0);
      float ap1 = c01*__expf(-la1);
      float q0 = ap0, q1 = ap1;
      #pragma unroll
      for (int off=32; off; off>>=1){
        q0 += __shfl_xor(q0, off);
        q1 += __shfl_xor(q1, off);
      }
      wg0 = ap0/(q0 + EPSF)*av0;
      wg1 = ap1/(q1 + EPSF)*av1;
    } else {
      wg0 = av0; wg1 = av1;
    }
    wsa += wg0; wsb += wg1;
    #pragma unroll
    for (int e=0;e<16;++e){
      float t0 = wg0*V0[e]; S1a[e]+=t0; S2a[e]+=t0*V0[e];
      float t1 = wg1*V1[e]; S1b[e]+=t1; S2b[e]+=t1*V1[e];
    }
  }

  // store partials: each wave owns distinct b -> no cross-wave reduction
  const size_t ba = (((size_t)b0*CH + c)*NO + lane);
  const size_t bb = (((size_t)b1*CH + c)*NO + lane);
  #pragma unroll
  for (int e=0;e<16;++e){
    S1p[ba*ND+e]=S1a[e]; S2p[ba*ND+e]=S2a[e];
    S1p[bb*ND+e]=S1b[e]; S2p[bb*ND+e]=S2b[e];
  }
  if (ESTEP){ Wsp[ba] = wsa; Wsp[bb] = wsb; }
}

// ---------------- reduce m-step partials -> mean0,i2v0,c0 -------------------
__global__ __launch_bounds__(64) void k_mred(
    const float* __restrict__ beta_a, const float* __restrict__ beta_u,
    const float* __restrict__ S1p, const float* __restrict__ S2p,
    const float* __restrict__ asum, const int CH,
    float* __restrict__ mean0, float* __restrict__ i2v0, float* __restrict__ c0)
{
  const int bo = blockIdx.x;
  const int b = bo >> 6, o = bo & 63;
  const int t = threadIdx.x;
  __shared__ float S1s[16], S2s[16];
  __shared__ float ct_s[16], vt_s[16];
  if (t < 16){
    float s = 0.f;
    for (int c=0;c<CH;++c) s += S1p[((((size_t)b*CH)+c)*NO + o)*ND + t];
    S1s[t] = s;
  } else if (t < 32){
    const int e = t - 16; float s = 0.f;
    for (int c=0;c<CH;++c) s += S2p[((((size_t)b*CH)+c)*NO + o)*ND + e];
    S2s[e] = s;
  }
  __syncthreads();
  if (t < 16){
    const float rrsum = asum[b] * (1.f/64.f);
    float T1 = S1s[t]*(1.f/64.f);
    float T2 = S2s[t]*(1.f/64.f);
    float m  = T1/(rrsum + EPSF);
    float var = (T2 - 2.f*m*T1 + m*m*rrsum)/(rrsum + EPSF) + 1e-4f;
    const size_t mbase = ((size_t)b*NO + o)*ND;
    mean0[mbase+t] = m;
    i2v0[mbase+t]  = 1.f/(2.f*var + EPSF);
    ct_s[t] = beta_u[o] + __logf(var);
    vt_s[t] = var;
  }
  __syncthreads();
  if (t == 0){
    const float rrsum = asum[b] * (1.f/64.f);
    float cost = 0.f, prod = 1.f;
    #pragma unroll
    for (int e=0;e<16;++e){ cost += ct_s[e]; prod *= vt_s[e]; }
    cost *= rrsum;
    float x  = 5.0e-4f*(beta_a[o] - cost);   // inv_temp iter0 = 0.01*(1-0.95)
    float aj = 1.f/(1.f + __expf(-x));
    float p1 = sqrtf(6.2831853071795864f*prod + EPSF);
    c0[(size_t)b*NO + o] = aj/(p1 + EPSF);
  }
}

// ---------------- final: reduce e-partials, write output (fp32) -------------
__global__ __launch_bounds__(64) void k_final(
    const float* __restrict__ beta_a, const float* __restrict__ beta_u,
    const float* __restrict__ S1p, const float* __restrict__ S2p,
    const float* __restrict__ Wsp, const int CH,
    float* __restrict__ out)
{
  const int bo = blockIdx.x;
  const int b = bo >> 6, o = bo & 63;
  const int t = threadIdx.x;
  __shared__ float S1s[16], S2s[16], Wss;
  __shared__ float mean_s[16], ct_s[16], nt_s[16];
  __shared__ float scale_s;
  if (t < 16){
    float s = 0.f;
    for (int c=0;c<CH;++c) s += S1p[((((size_t)b*CH)+c)*NO + o)*ND + t];
    S1s[t] = s;
  } else if (t < 32){
    const int e = t - 16; float s = 0.f;
    for (int c=0;c<CH;++c) s += S2p[((((size_t)b*CH)+c)*NO + o)*ND + e];
    S2s[e] = s;
  } else if (t == 32){
    float s = 0.f;
    for (int c=0;c<CH;++c) s += Wsp[(((size_t)b*CH)+c)*NO + o];
    Wss = s;
  }
  __syncthreads();
  const float Wsum = Wss;
  if (t < 16){
    float S1 = S1s[t], S2 = S2s[t];
    float m = S1/(Wsum + EPSF);
    float var = (S2 - 2.f*m*S1 + m*m*Wsum)/(Wsum + EPSF) + 1e-4f;
    mean_s[t] = m;
    ct_s[t] = beta_u[o] + __logf(var);
    float me = m + EPSF;
    nt_s[t] = me*me;
  }
  __syncthreads();
  if (t == 0){
    float cost=0.f, nrm=0.f;
    #pragma unroll
    for (int e=0;e<16;++e){ cost += ct_s[e]; nrm += nt_s[e]; }
    cost *= Wsum;
    float x = 9.75e-4f*(beta_a[o] - cost);  // inv_temp iter1 = 0.01*(1-0.95^2)
    float aj = 1.f/(1.f + __expf(-x));
    scale_s = aj/(sqrtf(nrm) + EPSF);
  }
  __syncthreads();
  if (t < 16){
    out[(size_t)bo*ND + t] = scale_s*mean_s[t];   // fp32 store
  }
}

// ---------------- host ------------------------------------------------------
extern "C" void kernel_launch(void* const* d_in, const int* in_sizes, int n_in,
                              void* d_out, int out_size, void* d_ws, size_t ws_size,
                              hipStream_t stream)
{
  const float* u      = (const float*)d_in[0];
  const float* W      = (const float*)d_in[1];
  const float* beta_a = (const float*)d_in[2];
  const float* beta_u = (const float*)d_in[3];
  const float* bias   = (const float*)d_in[4];
  float* ws  = (float*)d_ws;
  float* out = (float*)d_out;

  const size_t base_f = (size_t)NB + 2u*NB*NO*ND + NB*NO;        // 135,232 floats
  const size_t per_ch = 2u*(size_t)NB*NO*ND + (size_t)NB*NO;    // 135,168 floats/chunk
  int CH = 8;
  if (ws_size >= (base_f + per_ch*32)*4) CH = 32;

  float* asum = ws;
  float* mean0= asum + NB;
  float* i2v0 = mean0 + (size_t)NB*NO*ND;
  float* c0   = i2v0 + (size_t)NB*NO*ND;
  float* S1p  = c0   + (size_t)NB*NO;
  float* S2p  = S1p  + (size_t)NB*CH*NO*ND;
  float* Wsp  = S2p  + (size_t)NB*CH*NO*ND;

  const int GRID = 8*CH;   // bg-major: bid = bg*CH + c  -> same-c same XCD slot

  k_ai<<<NB, 256, 0, stream>>>(u, asum);
  k_heavy<false><<<GRID, 256, 0, stream>>>(u, W, bias,
                                           nullptr, nullptr, nullptr,
                                           S1p, S2p, nullptr, CH);
  k_mred<<<NB*NO, 64, 0, stream>>>(beta_a, beta_u, S1p, S2p, asum, CH,
                                   mean0, i2v0, c0);
  k_heavy<true><<<GRID, 256, 0, stream>>>(u, W, bias,
                                          mean0, i2v0, c0,
                                          S1p, S2p, Wsp, CH);
  k_final<<<NB*NO, 64, 0, stream>>>(beta_a, beta_u, S1p, S2p, Wsp, CH, out);
}

// Round 8
// 420.899 us; speedup vs baseline: 3.0612x; 1.1292x over previous
//
#include <hip/hip_runtime.h>

#define EPSF 1e-8f

constexpr int NB = 64;   // batch
constexpr int NO = 64;   // out capsules
constexpr int NI = 1152; // in capsules
constexpr int ND = 16;   // pose dims

constexpr int RSTRIDE = 260;            // 256 floats + 4 pad (16B-aligned rows)
constexpr int BUFSZ   = 64 * RSTRIDE;   // one W-tile: 64 o-rows

// fp32 row loader ------------------------------------------------------------
__device__ __forceinline__ void loadrow16f(const float* __restrict__ base,
                                           size_t elem, float* f){
  const float4* p = (const float4*)(base + elem);
  float4 x0=p[0], x1=p[1], x2=p[2], x3=p[3];
  f[0]=x0.x; f[1]=x0.y; f[2]=x0.z; f[3]=x0.w;
  f[4]=x1.x; f[5]=x1.y; f[6]=x1.z; f[7]=x1.w;
  f[8]=x2.x; f[9]=x2.y; f[10]=x2.z; f[11]=x2.w;
  f[12]=x3.x; f[13]=x3.y; f[14]=x3.z; f[15]=x3.w;
}

// async global->LDS, 16 B per lane; lds dst must be wave-uniform base
__device__ __forceinline__ void gl_lds16(const float* g, float* l){
  __builtin_amdgcn_global_load_lds(
      (const __attribute__((address_space(1))) unsigned int*)g,
      (__attribute__((address_space(3))) unsigned int*)l,
      16, 0, 0);
}

// ---------------- heavy kernel --------------------------------------------
// grid 1-D: bid = bg*CH + c (same-c blocks -> same bid%8 -> same XCD; W slice
// 2.36MB stays in that XCD's L2). Block = 4 waves; wave w owns b0=bg*8+2w,+1.
// Per i: W[:,i,:,:] (64KB) DMA'd to LDS rows [o][256] stride 260 (double-buf);
// lane=o reads its row via ds_read_b128 (conflict-free: 8-lane groups cover
// all 32 banks); V, softmax (wave shuffle over o), moments all in registers.
template<bool ESTEP>
__global__ __launch_bounds__(256, 1) void k_heavy(
    const float* __restrict__ u, const float* __restrict__ W,
    const float* __restrict__ bias,
    const float* __restrict__ mean0, const float* __restrict__ i2v0,
    const float* __restrict__ c0,
    float* __restrict__ S1p, float* __restrict__ S2p, float* __restrict__ Wsp,
    const int CH)
{
  const int CI = NI / CH;
  const int bid = blockIdx.x;
  const int bg = bid / CH, c = bid % CH;
  const int t = threadIdx.x, lane = t & 63, w = t >> 6;
  const int b0 = bg*8 + 2*w, b1 = b0 + 1;
  const int i0 = c*CI;

  __shared__ float buf[2*BUFSZ];   // 133,120 B

  // per-lane (=o) constants
  float bs[16]; loadrow16f(bias, (size_t)lane*ND, bs);
  float mr0[16], ir0[16], mr1[16], ir1[16]; float c00 = 0.f, c01 = 0.f;
  if (ESTEP){
    const size_t m0 = ((size_t)b0*NO + lane)*ND;
    const size_t m1 = ((size_t)b1*NO + lane)*ND;
    #pragma unroll
    for (int e=0;e<16;++e){ mr0[e]=mean0[m0+e]; ir0[e]=i2v0[m0+e];
                            mr1[e]=mean0[m1+e]; ir1[e]=i2v0[m1+e]; }
    c00 = c0[(size_t)b0*NO + lane];
    c01 = c0[(size_t)b1*NO + lane];
  }

  float S1a[16], S2a[16], S1b[16], S2b[16];
  float wsa = 0.f, wsb = 0.f;
  #pragma unroll
  for (int e=0;e<16;++e){ S1a[e]=0.f; S2a[e]=0.f; S1b[e]=0.f; S2b[e]=0.f; }

  // stage W tile for row index i into buffer p: wave w covers o = w*16..w*16+15
  auto stage = [&](int p, int i){
    const float* gbase = W + (size_t)i*256 + (size_t)lane*4;
    float* lbase = &buf[p*BUFSZ];
    #pragma unroll
    for (int r=0;r<16;++r){
      const int o = w*16 + r;
      gl_lds16(gbase + (size_t)o*NI*256, lbase + o*RSTRIDE);
    }
  };

  int p = 0;
  stage(0, i0);

  for (int ii=0; ii<CI; ++ii){
    __syncthreads();                 // drains tile-p loads; syncs buffer reuse
    if (ii+1 < CI) stage(p^1, i0+ii+1);   // async, overlaps compute below

    const int i = i0 + ii;
    // u rows (wave-uniform addresses -> broadcast loads)
    float u0[16], u1[16];
    loadrow16f(u, ((size_t)b0*NI + i)*ND, u0);
    loadrow16f(u, ((size_t)b1*NI + i)*ND, u1);
    float s0=0.f, s1=0.f;
    #pragma unroll
    for (int d=0;d<16;++d){
      float x0=u0[d]+EPSF; s0 += x0*x0;
      float x1=u1[d]+EPSF; s1 += x1*x1;
    }
    const float av0 = sqrtf(s0), av1 = sqrtf(s1);

    // V for this lane's o, both batches (wide LDS reads)
    float V0[16], V1[16];
    #pragma unroll
    for (int e=0;e<16;++e){ V0[e]=bs[e]+EPSF; V1[e]=bs[e]+EPSF; }
    const float* row = &buf[p*BUFSZ + lane*RSTRIDE];
    #pragma unroll
    for (int e=0;e<16;++e){
      #pragma unroll
      for (int dq=0; dq<4; ++dq){
        const float4 wv = *(const float4*)(row + e*16 + dq*4);
        const int d = dq*4;
        V0[e] += wv.x*u0[d+0] + wv.y*u0[d+1] + wv.z*u0[d+2] + wv.w*u0[d+3];
        V1[e] += wv.x*u1[d+0] + wv.y*u1[d+1] + wv.z*u1[d+2] + wv.w*u1[d+3];
      }
    }

    float wg0, wg1;
    if (ESTEP){
      float la0=0.f, la1=0.f;
      #pragma unroll
      for (int e=0;e<16;++e){
        float d0=V0[e]-mr0[e]; la0 += d0*d0*ir0[e];
        float d1=V1[e]-mr1[e]; la1 += d1*d1*ir1[e];
      }
      float ap0 = c00*__expf(-la0);
      float ap1 = c01*__expf(-la1);
      float q0 = ap0, q1 = ap1;
      #pragma unroll
      for (int off=32; off; off>>=1){
        q0 += __shfl_xor(q0, off);
        q1 += __shfl_xor(q1, off);
      }
      wg0 = ap0/(q0 + EPSF)*av0;
      wg1 = ap1/(q1 + EPSF)*av1;
    } else {
      wg0 = av0; wg1 = av1;   // uniform rr: 1/64 applied in k_mred
    }
    wsa += wg0; wsb += wg1;
    #pragma unroll
    for (int e=0;e<16;++e){
      float t0 = wg0*V0[e]; S1a[e]+=t0; S2a[e]+=t0*V0[e];
      float t1 = wg1*V1[e]; S1b[e]+=t1; S2b[e]+=t1*V1[e];
    }
    p ^= 1;
  }

  // store partials: each wave owns distinct b -> no cross-wave reduction
  const size_t ba = (((size_t)b0*CH + c)*NO + lane);
  const size_t bb = (((size_t)b1*CH + c)*NO + lane);
  #pragma unroll
  for (int e=0;e<16;++e){
    S1p[ba*ND+e]=S1a[e]; S2p[ba*ND+e]=S2a[e];
    S1p[bb*ND+e]=S1b[e]; S2p[bb*ND+e]=S2b[e];
  }
  Wsp[ba] = wsa; Wsp[bb] = wsb;    // m-pass: chunk sum of a_i; e-pass: rr*a sum
}

// ---------------- reduce m-step partials -> mean0,i2v0,c0 -------------------
__global__ __launch_bounds__(64) void k_mred(
    const float* __restrict__ beta_a, const float* __restrict__ beta_u,
    const float* __restrict__ S1p, const float* __restrict__ S2p,
    const float* __restrict__ Wsp, const int CH,
    float* __restrict__ mean0, float* __restrict__ i2v0, float* __restrict__ c0)
{
  const int bo = blockIdx.x;
  const int b = bo >> 6, o = bo & 63;
  const int t = threadIdx.x;
  __shared__ float S1s[16], S2s[16], Wss;
  __shared__ float ct_s[16], vt_s[16];
  if (t < 16){
    float s = 0.f;
    for (int c=0;c<CH;++c) s += S1p[((((size_t)b*CH)+c)*NO + o)*ND + t];
    S1s[t] = s;
  } else if (t < 32){
    const int e = t - 16; float s = 0.f;
    for (int c=0;c<CH;++c) s += S2p[((((size_t)b*CH)+c)*NO + o)*ND + e];
    S2s[e] = s;
  } else if (t == 32){
    float s = 0.f;
    for (int c=0;c<CH;++c) s += Wsp[(((size_t)b*CH)+c)*NO + o];
    Wss = s;                       // = asum[b] (sum of a_i)
  }
  __syncthreads();
  const float rrsum = Wss * (1.f/64.f);
  if (t < 16){
    float T1 = S1s[t]*(1.f/64.f);
    float T2 = S2s[t]*(1.f/64.f);
    float m  = T1/(rrsum + EPSF);
    float var = (T2 - 2.f*m*T1 + m*m*rrsum)/(rrsum + EPSF) + 1e-4f;
    const size_t mbase = ((size_t)b*NO + o)*ND;
    mean0[mbase+t] = m;
    i2v0[mbase+t]  = 1.f/(2.f*var + EPSF);
    ct_s[t] = beta_u[o] + __logf(var);
    vt_s[t] = var;
  }
  __syncthreads();
  if (t == 0){
    float cost = 0.f, prod = 1.f;
    #pragma unroll
    for (int e=0;e<16;++e){ cost += ct_s[e]; prod *= vt_s[e]; }
    cost *= rrsum;
    float x  = 5.0e-4f*(beta_a[o] - cost);   // inv_temp iter0 = 0.01*(1-0.95)
    float aj = 1.f/(1.f + __expf(-x));
    float p1 = sqrtf(6.2831853071795864f*prod + EPSF);
    c0[(size_t)b*NO + o] = aj/(p1 + EPSF);
  }
}

// ---------------- final: reduce e-partials, write output (fp32) -------------
__global__ __launch_bounds__(64) void k_final(
    const float* __restrict__ beta_a, const float* __restrict__ beta_u,
    const float* __restrict__ S1p, const float* __restrict__ S2p,
    const float* __restrict__ Wsp, const int CH,
    float* __restrict__ out)
{
  const int bo = blockIdx.x;
  const int b = bo >> 6, o = bo & 63;
  const int t = threadIdx.x;
  __shared__ float S1s[16], S2s[16], Wss;
  __shared__ float mean_s[16], ct_s[16], nt_s[16];
  __shared__ float scale_s;
  if (t < 16){
    float s = 0.f;
    for (int c=0;c<CH;++c) s += S1p[((((size_t)b*CH)+c)*NO + o)*ND + t];
    S1s[t] = s;
  } else if (t < 32){
    const int e = t - 16; float s = 0.f;
    for (int c=0;c<CH;++c) s += S2p[((((size_t)b*CH)+c)*NO + o)*ND + e];
    S2s[e] = s;
  } else if (t == 32){
    float s = 0.f;
    for (int c=0;c<CH;++c) s += Wsp[(((size_t)b*CH)+c)*NO + o];
    Wss = s;
  }
  __syncthreads();
  const float Wsum = Wss;
  if (t < 16){
    float S1 = S1s[t], S2 = S2s[t];
    float m = S1/(Wsum + EPSF);
    float var = (S2 - 2.f*m*S1 + m*m*Wsum)/(Wsum + EPSF) + 1e-4f;
    mean_s[t] = m;
    ct_s[t] = beta_u[o] + __logf(var);
    float me = m + EPSF;
    nt_s[t] = me*me;
  }
  __syncthreads();
  if (t == 0){
    float cost=0.f, nrm=0.f;
    #pragma unroll
    for (int e=0;e<16;++e){ cost += ct_s[e]; nrm += nt_s[e]; }
    cost *= Wsum;
    float x = 9.75e-4f*(beta_a[o] - cost);  // inv_temp iter1 = 0.01*(1-0.95^2)
    float aj = 1.f/(1.f + __expf(-x));
    scale_s = aj/(sqrtf(nrm) + EPSF);
  }
  __syncthreads();
  if (t < 16){
    out[(size_t)bo*ND + t] = scale_s*mean_s[t];   // fp32 store
  }
}

// ---------------- host ------------------------------------------------------
extern "C" void kernel_launch(void* const* d_in, const int* in_sizes, int n_in,
                              void* d_out, int out_size, void* d_ws, size_t ws_size,
                              hipStream_t stream)
{
  const float* u      = (const float*)d_in[0];
  const float* W      = (const float*)d_in[1];
  const float* beta_a = (const float*)d_in[2];
  const float* beta_u = (const float*)d_in[3];
  const float* bias   = (const float*)d_in[4];
  float* ws  = (float*)d_ws;
  float* out = (float*)d_out;

  const size_t base_f = 2u*NB*NO*ND + NB*NO;                  // 135,168 floats
  const size_t per_ch = 2u*(size_t)NB*NO*ND + (size_t)NB*NO;  // 135,168 floats/chunk
  int CH = 8;
  if (ws_size >= (base_f + per_ch*32)*4) CH = 32;

  float* mean0= ws;
  float* i2v0 = mean0 + (size_t)NB*NO*ND;
  float* c0   = i2v0 + (size_t)NB*NO*ND;
  float* S1p  = c0   + (size_t)NB*NO;
  float* S2p  = S1p  + (size_t)NB*CH*NO*ND;
  float* Wsp  = S2p  + (size_t)NB*CH*NO*ND;

  const int GRID = 8*CH;   // bid = bg*CH + c -> same-c blocks share an XCD

  k_heavy<false><<<GRID, 256, 0, stream>>>(u, W, bias,
                                           nullptr, nullptr, nullptr,
                                           S1p, S2p, Wsp, CH);
  k_mred<<<NB*NO, 64, 0, stream>>>(beta_a, beta_u, S1p, S2p, Wsp, CH,
                                   mean0, i2v0, c0);
  k_heavy<true><<<GRID, 256, 0, stream>>>(u, W, bias,
                                          mean0, i2v0, c0,
                                          S1p, S2p, Wsp, CH);
  k_final<<<NB*NO, 64, 0, stream>>>(beta_a, beta_u, S1p, S2p, Wsp, CH, out);
}

// Round 9
// 408.865 us; speedup vs baseline: 3.1513x; 1.0294x over previous
//
#include <hip/hip_runtime.h>

#define EPSF 1e-8f

constexpr int NB = 64;   // batch
constexpr int NO = 64;   // out capsules
constexpr int NI = 1152; // in capsules
constexpr int ND = 16;   // pose dims

constexpr int RSTRIDE = 260;            // 256 floats + 4 pad (16B-aligned rows)
constexpr int BUFSZ   = 64 * RSTRIDE;   // one W-tile: 64 o-rows

typedef float v2f __attribute__((ext_vector_type(2)));

// fp32 row loader ------------------------------------------------------------
__device__ __forceinline__ void loadrow16f(const float* __restrict__ base,
                                           size_t elem, float* f){
  const float4* p = (const float4*)(base + elem);
  float4 x0=p[0], x1=p[1], x2=p[2], x3=p[3];
  f[0]=x0.x; f[1]=x0.y; f[2]=x0.z; f[3]=x0.w;
  f[4]=x1.x; f[5]=x1.y; f[6]=x1.z; f[7]=x1.w;
  f[8]=x2.x; f[9]=x2.y; f[10]=x2.z; f[11]=x2.w;
  f[12]=x3.x; f[13]=x3.y; f[14]=x3.z; f[15]=x3.w;
}

// async global->LDS, 16 B per lane; lds dst is wave-uniform base + lane*16
__device__ __forceinline__ void gl_lds16(const float* g, float* l){
  __builtin_amdgcn_global_load_lds(
      (const __attribute__((address_space(1))) unsigned int*)g,
      (__attribute__((address_space(3))) unsigned int*)l,
      16, 0, 0);
}

// ---------------- heavy kernel --------------------------------------------
// grid 1-D: bid = bg*CH + c (CH%8==0 -> same-c blocks share bid%8 -> same XCD;
// W slice NI/CH cols stays in that XCD's L2). Block = NW waves; wave w owns
// batches b0=bg*2NW+2w, b1=b0+1 packed into float2 lanes (v_pk_fma_f32).
// Per i: W[:,i,:,:] (64KB) DMA'd to LDS rows [o][256] stride 260 (double-buf);
// lane=o reads its row via ds_read_b128 (conflict-free); V, softmax (wave
// shuffle over o), moments all in registers/packed.
template<int NW, bool ESTEP>
__global__ __launch_bounds__(NW*64, 2) void k_heavy(
    const float* __restrict__ u, const float* __restrict__ W,
    const float* __restrict__ bias,
    const float* __restrict__ mean0, const float* __restrict__ i2v0,
    const float* __restrict__ c0,
    float* __restrict__ S1p, float* __restrict__ S2p, float* __restrict__ Wsp,
    const int CH)
{
  const int CI = NI / CH;
  constexpr int ROWS = 64 / NW;
  const int bid = blockIdx.x;
  const int bg = bid / CH, c = bid % CH;
  const int t = threadIdx.x, lane = t & 63, w = t >> 6;
  const int b0 = bg*(2*NW) + 2*w, b1 = b0 + 1;
  const int i0 = c*CI;

  __shared__ float buf[2*BUFSZ];   // 133,120 B

  // per-lane (=o) constants
  float bs[16]; loadrow16f(bias, (size_t)lane*ND, bs);
  v2f mr[16], ir[16]; v2f c01 = {0.f, 0.f};
  if (ESTEP){
    const size_t m0 = ((size_t)b0*NO + lane)*ND;
    const size_t m1 = ((size_t)b1*NO + lane)*ND;
    #pragma unroll
    for (int e=0;e<16;++e){
      mr[e] = v2f{mean0[m0+e], mean0[m1+e]};
      ir[e] = v2f{i2v0[m0+e], i2v0[m1+e]};
    }
    c01 = v2f{c0[(size_t)b0*NO + lane], c0[(size_t)b1*NO + lane]};
  }

  v2f S1[16], S2[16]; v2f wsum = {0.f, 0.f};
  #pragma unroll
  for (int e=0;e<16;++e){ S1[e]=v2f{0.f,0.f}; S2[e]=v2f{0.f,0.f}; }

  // stage W tile for column i into buffer p: wave w covers ROWS o-rows
  auto stage = [&](int p, int i){
    const float* gbase = W + (size_t)i*256 + (size_t)lane*4;
    float* lbase = &buf[p*BUFSZ];
    #pragma unroll
    for (int r=0;r<ROWS;++r){
      const int o = w*ROWS + r;
      gl_lds16(gbase + (size_t)o*NI*256, lbase + o*RSTRIDE);
    }
  };

  int p = 0;
  stage(0, i0);

  for (int ii=0; ii<CI; ++ii){
    __syncthreads();                      // drains tile-p loads; buffer reuse
    if (ii+1 < CI) stage(p^1, i0+ii+1);   // async, overlaps compute below

    const int i = i0 + ii;
    // u rows for both batches, interleaved into float2 (broadcast loads)
    v2f u01[16];
    {
      const float4* pa = (const float4*)(u + ((size_t)b0*NI + i)*ND);
      const float4* pb = (const float4*)(u + ((size_t)b1*NI + i)*ND);
      #pragma unroll
      for (int q=0;q<4;++q){
        float4 xa = pa[q], xb = pb[q];
        u01[q*4+0] = v2f{xa.x, xb.x};
        u01[q*4+1] = v2f{xa.y, xb.y};
        u01[q*4+2] = v2f{xa.z, xb.z};
        u01[q*4+3] = v2f{xa.w, xb.w};
      }
    }
    v2f ss = {0.f, 0.f};
    #pragma unroll
    for (int d=0;d<16;++d){ v2f x = u01[d] + EPSF; ss += x*x; }
    const v2f av = {sqrtf(ss.x), sqrtf(ss.y)};

    // V for this lane's o, both batches packed (wide LDS reads)
    v2f V[16];
    #pragma unroll
    for (int e=0;e<16;++e){ float b = bs[e] + EPSF; V[e] = v2f{b, b}; }
    const float* row = &buf[p*BUFSZ + lane*RSTRIDE];
    #pragma unroll
    for (int e=0;e<16;++e){
      #pragma unroll
      for (int dq=0; dq<4; ++dq){
        const float4 wv = *(const float4*)(row + e*16 + dq*4);
        const int d = dq*4;
        V[e] += wv.x*u01[d+0];
        V[e] += wv.y*u01[d+1];
        V[e] += wv.z*u01[d+2];
        V[e] += wv.w*u01[d+3];
      }
    }

    v2f wg;
    if (ESTEP){
      v2f la = {0.f, 0.f};
      #pragma unroll
      for (int e=0;e<16;++e){ v2f df = V[e]-mr[e]; la += df*df*ir[e]; }
      v2f ap = c01 * v2f{__expf(-la.x), __expf(-la.y)};
      float q0 = ap.x, q1 = ap.y;
      #pragma unroll
      for (int off=32; off; off>>=1){
        q0 += __shfl_xor(q0, off);
        q1 += __shfl_xor(q1, off);
      }
      wg = v2f{ap.x/(q0 + EPSF)*av.x, ap.y/(q1 + EPSF)*av.y};
    } else {
      wg = av;                      // uniform rr: 1/64 applied in k_mred
    }
    wsum += wg;
    #pragma unroll
    for (int e=0;e<16;++e){
      v2f tv = wg*V[e]; S1[e]+=tv; S2[e]+=tv*V[e];
    }
    p ^= 1;
  }

  // store partials: each wave owns distinct b -> no cross-wave reduction
  const size_t ba = (((size_t)b0*CH + c)*NO + lane);
  const size_t bb = (((size_t)b1*CH + c)*NO + lane);
  #pragma unroll
  for (int e=0;e<16;++e){
    S1p[ba*ND+e]=S1[e].x; S2p[ba*ND+e]=S2[e].x;
    S1p[bb*ND+e]=S1[e].y; S2p[bb*ND+e]=S2[e].y;
  }
  Wsp[ba] = wsum.x; Wsp[bb] = wsum.y;  // m-pass: sum a_i; e-pass: sum rr*a
}

// ---------------- reduce m-step partials -> mean0,i2v0,c0 -------------------
__global__ __launch_bounds__(64) void k_mred(
    const float* __restrict__ beta_a, const float* __restrict__ beta_u,
    const float* __restrict__ S1p, const float* __restrict__ S2p,
    const float* __restrict__ Wsp, const int CH,
    float* __restrict__ mean0, float* __restrict__ i2v0, float* __restrict__ c0)
{
  const int bo = blockIdx.x;
  const int b = bo >> 6, o = bo & 63;
  const int t = threadIdx.x;
  __shared__ float S1s[16], S2s[16], Wss;
  __shared__ float ct_s[16], vt_s[16];
  if (t < 16){
    float s = 0.f;
    for (int c=0;c<CH;++c) s += S1p[((((size_t)b*CH)+c)*NO + o)*ND + t];
    S1s[t] = s;
  } else if (t < 32){
    const int e = t - 16; float s = 0.f;
    for (int c=0;c<CH;++c) s += S2p[((((size_t)b*CH)+c)*NO + o)*ND + e];
    S2s[e] = s;
  } else if (t == 32){
    float s = 0.f;
    for (int c=0;c<CH;++c) s += Wsp[(((size_t)b*CH)+c)*NO + o];
    Wss = s;                       // = asum[b]
  }
  __syncthreads();
  const float rrsum = Wss * (1.f/64.f);
  if (t < 16){
    float T1 = S1s[t]*(1.f/64.f);
    float T2 = S2s[t]*(1.f/64.f);
    float m  = T1/(rrsum + EPSF);
    float var = (T2 - 2.f*m*T1 + m*m*rrsum)/(rrsum + EPSF) + 1e-4f;
    const size_t mbase = ((size_t)b*NO + o)*ND;
    mean0[mbase+t] = m;
    i2v0[mbase+t]  = 1.f/(2.f*var + EPSF);
    ct_s[t] = beta_u[o] + __logf(var);
    vt_s[t] = var;
  }
  __syncthreads();
  if (t == 0){
    float cost = 0.f, prod = 1.f;
    #pragma unroll
    for (int e=0;e<16;++e){ cost += ct_s[e]; prod *= vt_s[e]; }
    cost *= rrsum;
    float x  = 5.0e-4f*(beta_a[o] - cost);   // inv_temp iter0 = 0.01*(1-0.95)
    float aj = 1.f/(1.f + __expf(-x));
    float p1 = sqrtf(6.2831853071795864f*prod + EPSF);
    c0[(size_t)b*NO + o] = aj/(p1 + EPSF);
  }
}

// ---------------- final: reduce e-partials, write output (fp32) -------------
__global__ __launch_bounds__(64) void k_final(
    const float* __restrict__ beta_a, const float* __restrict__ beta_u,
    const float* __restrict__ S1p, const float* __restrict__ S2p,
    const float* __restrict__ Wsp, const int CH,
    float* __restrict__ out)
{
  const int bo = blockIdx.x;
  const int b = bo >> 6, o = bo & 63;
  const int t = threadIdx.x;
  __shared__ float S1s[16], S2s[16], Wss;
  __shared__ float mean_s[16], ct_s[16], nt_s[16];
  __shared__ float scale_s;
  if (t < 16){
    float s = 0.f;
    for (int c=0;c<CH;++c) s += S1p[((((size_t)b*CH)+c)*NO + o)*ND + t];
    S1s[t] = s;
  } else if (t < 32){
    const int e = t - 16; float s = 0.f;
    for (int c=0;c<CH;++c) s += S2p[((((size_t)b*CH)+c)*NO + o)*ND + e];
    S2s[e] = s;
  } else if (t == 32){
    float s = 0.f;
    for (int c=0;c<CH;++c) s += Wsp[(((size_t)b*CH)+c)*NO + o];
    Wss = s;
  }
  __syncthreads();
  const float Wsum = Wss;
  if (t < 16){
    float S1 = S1s[t], S2 = S2s[t];
    float m = S1/(Wsum + EPSF);
    float var = (S2 - 2.f*m*S1 + m*m*Wsum)/(Wsum + EPSF) + 1e-4f;
    mean_s[t] = m;
    ct_s[t] = beta_u[o] + __logf(var);
    float me = m + EPSF;
    nt_s[t] = me*me;
  }
  __syncthreads();
  if (t == 0){
    float cost=0.f, nrm=0.f;
    #pragma unroll
    for (int e=0;e<16;++e){ cost += ct_s[e]; nrm += nt_s[e]; }
    cost *= Wsum;
    float x = 9.75e-4f*(beta_a[o] - cost);  // inv_temp iter1 = 0.01*(1-0.95^2)
    float aj = 1.f/(1.f + __expf(-x));
    scale_s = aj/(sqrtf(nrm) + EPSF);
  }
  __syncthreads();
  if (t < 16){
    out[(size_t)bo*ND + t] = scale_s*mean_s[t];   // fp32 store
  }
}

// ---------------- host ------------------------------------------------------
extern "C" void kernel_launch(void* const* d_in, const int* in_sizes, int n_in,
                              void* d_out, int out_size, void* d_ws, size_t ws_size,
                              hipStream_t stream)
{
  const float* u      = (const float*)d_in[0];
  const float* W      = (const float*)d_in[1];
  const float* beta_a = (const float*)d_in[2];
  const float* beta_u = (const float*)d_in[3];
  const float* bias   = (const float*)d_in[4];
  float* ws  = (float*)d_ws;
  float* out = (float*)d_out;

  const size_t base_f = 2u*NB*NO*ND + NB*NO;                  // 135,168 floats
  auto need = [&](int ch){
    return (base_f + 2u*(size_t)NB*ch*NO*ND + (size_t)NB*ch*NO)*4;
  };
  const bool big = (ws_size >= need(64));     // 512-thr / CH=64 path
  const int CH = big ? 64 : 32;

  float* mean0= ws;
  float* i2v0 = mean0 + (size_t)NB*NO*ND;
  float* c0   = i2v0 + (size_t)NB*NO*ND;
  float* S1p  = c0   + (size_t)NB*NO;
  float* S2p  = S1p  + (size_t)NB*CH*NO*ND;
  float* Wsp  = S2p  + (size_t)NB*CH*NO*ND;

  if (big){
    const int GRID = (NB/16)*CH;   // 256 blocks of 8 waves -> 2 waves/SIMD
    k_heavy<8,false><<<GRID, 512, 0, stream>>>(u, W, bias,
                                               nullptr, nullptr, nullptr,
                                               S1p, S2p, Wsp, CH);
    k_mred<<<NB*NO, 64, 0, stream>>>(beta_a, beta_u, S1p, S2p, Wsp, CH,
                                     mean0, i2v0, c0);
    k_heavy<8,true><<<GRID, 512, 0, stream>>>(u, W, bias,
                                              mean0, i2v0, c0,
                                              S1p, S2p, Wsp, CH);
  } else {
    const int GRID = (NB/8)*CH;    // proven R8 shape
    k_heavy<4,false><<<GRID, 256, 0, stream>>>(u, W, bias,
                                               nullptr, nullptr, nullptr,
                                               S1p, S2p, Wsp, CH);
    k_mred<<<NB*NO, 64, 0, stream>>>(beta_a, beta_u, S1p, S2p, Wsp, CH,
                                     mean0, i2v0, c0);
    k_heavy<4,true><<<GRID, 256, 0, stream>>>(u, W, bias,
                                              mean0, i2v0, c0,
                                              S1p, S2p, Wsp, CH);
  }
  k_final<<<NB*NO, 64, 0, stream>>>(beta_a, beta_u, S1p, S2p, Wsp, CH, out);
}